// Round 1
// baseline (76.119 us; speedup 1.0000x reference)
//
#include <hip/hip_runtime.h>

typedef unsigned short ushort_t;
typedef __bf16 bf16x8 __attribute__((ext_vector_type(8)));
typedef float f32x4 __attribute__((ext_vector_type(4)));

static __device__ __forceinline__ ushort_t f2bf(float f) {
    __bf16 b = (__bf16)f;   // RNE convert
    return __builtin_bit_cast(ushort_t, b);
}

#define GLOAD_LDS16(gptr, lptr)                                                        \
    __builtin_amdgcn_global_load_lds(                                                  \
        (const __attribute__((address_space(1))) void*)(gptr),                         \
        (__attribute__((address_space(3))) void*)(lptr), 16, 0, 0)

// ---------------------------------------------------------------------------
// fp32 -> bf16 convert, 4 elems/thread/iter
__global__ void cvt4(const float* __restrict__ in, ushort_t* __restrict__ out, int n4) {
    int i = blockIdx.x * blockDim.x + threadIdx.x;
    int stride = gridDim.x * blockDim.x;
    for (; i < n4; i += stride) {
        float4 v = ((const float4*)in)[i];
        ushort4 o;
        o.x = f2bf(v.x); o.y = f2bf(v.y); o.z = f2bf(v.z); o.w = f2bf(v.w);
        ((ushort4*)out)[i] = o;
    }
}

// ---------------------------------------------------------------------------
// Pt[c][j] = bf16(w_in[r(j)][c]),  r(j) = (j>>6)*192 + 128 + (j&63)
// 64x64 tile per block via LDS (coalesced read and write)
__global__ void gather_tr(const float* __restrict__ w_in, ushort_t* __restrict__ Pt) {
    __shared__ ushort_t tile[64][65];
    const int j0 = blockIdx.x * 64;   // v-channel tile
    const int c0 = blockIdx.y * 64;   // input-channel tile
    const int t = threadIdx.x;
    #pragma unroll
    for (int p = 0; p < 16; ++p) {
        int e = p * 256 + t;
        int j = e >> 6, c = e & 63;
        int r = blockIdx.x * 192 + 128 + j;   // r(j0+j), j0 multiple of 64
        tile[j][c] = f2bf(w_in[(size_t)r * 1024 + c0 + c]);
    }
    __syncthreads();
    #pragma unroll
    for (int p = 0; p < 16; ++p) {
        int e = p * 256 + t;
        int c = e >> 6, j = e & 63;
        Pt[(size_t)(c0 + c) * 1024 + j0 + j] = tile[j][c];
    }
}

// ---------------------------------------------------------------------------
// bfused[i] = b_out[i] + sum_j w_out[i][j] * b_in[r(j)]
__global__ void fuse_bias(const float* __restrict__ w_out, const float* __restrict__ b_in,
                          const float* __restrict__ b_out, float* __restrict__ bfused) {
    const int i = blockIdx.x * 4 + (threadIdx.x >> 6);
    const int lane = threadIdx.x & 63;
    float s = 0.f;
    for (int j = lane; j < 1024; j += 64) {
        int r = (j >> 6) * 192 + 128 + (j & 63);
        s += w_out[(size_t)i * 1024 + j] * b_in[r];
    }
    #pragma unroll
    for (int off = 32; off; off >>= 1) s += __shfl_down(s, off, 64);
    if (lane == 0) bfused[i] = s + b_out[i];
}

// ---------------------------------------------------------------------------
// C[M][N] = A[M][K] @ B[N][K]^T (+ bias[n]), bf16 in, fp32 or bf16 out.
// 128x128 tile, 4 waves (2x2), BK=32, global_load_lds width-16 staging,
// mfma_f32_16x16x32_bf16.  K, lda=ldb=K, ldc=N all = 1024 here.
template <bool BF16_OUT>
__global__ __launch_bounds__(256)
void gemm_abt(const ushort_t* __restrict__ A, const ushort_t* __restrict__ B,
              const float* __restrict__ bias, void* __restrict__ C,
              const int K, const int N) {
    __shared__ alignas(16) ushort_t lsA[128 * 32];
    __shared__ alignas(16) ushort_t lsB[128 * 32];

    const int tid  = threadIdx.x;
    const int lane = tid & 63;
    const int wv   = tid >> 6;       // 0..3
    const int wr   = wv >> 1;        // wave row 0..1
    const int wc   = wv & 1;         // wave col 0..1
    const int fr   = lane & 15;      // fragment row index
    const int fq   = lane >> 4;      // 0..3 (k-subgroup)

    const int rA = blockIdx.y * 128;
    const int rB = blockIdx.x * 128;

    // staging coords: issue p covers rows [p*64+wv*16, +16), lane l -> row +l/4, col (l&3)*8
    const int st_row = wv * 16 + (lane >> 2);
    const int st_col = (lane & 3) * 8;

    f32x4 acc[4][4] = {};

    for (int k0 = 0; k0 < K; k0 += 32) {
        #pragma unroll
        for (int p = 0; p < 2; ++p) {
            const int row = p * 64 + st_row;
            GLOAD_LDS16(A + (size_t)(rA + row) * K + k0 + st_col, &lsA[p * 2048 + wv * 512]);
            GLOAD_LDS16(B + (size_t)(rB + row) * K + k0 + st_col, &lsB[p * 2048 + wv * 512]);
        }
        __syncthreads();   // compiler emits vmcnt(0) drain before barrier

        bf16x8 af[4], bfv[4];
        #pragma unroll
        for (int i = 0; i < 4; ++i)
            af[i] = *(const bf16x8*)&lsA[(wr * 64 + i * 16 + fr) * 32 + fq * 8];
        #pragma unroll
        for (int j = 0; j < 4; ++j)
            bfv[j] = *(const bf16x8*)&lsB[(wc * 64 + j * 16 + fr) * 32 + fq * 8];

        #pragma unroll
        for (int i = 0; i < 4; ++i)
            #pragma unroll
            for (int j = 0; j < 4; ++j)
                acc[i][j] = __builtin_amdgcn_mfma_f32_16x16x32_bf16(af[i], bfv[j], acc[i][j], 0, 0, 0);

        __syncthreads();
    }

    // epilogue: D[row][col], row = (lane>>4)*4 + r, col = lane&15 within each 16x16 frag
    const int orow0 = rA + wr * 64 + fq * 4;
    const int ocol0 = rB + wc * 64 + fr;
    #pragma unroll
    for (int i = 0; i < 4; ++i) {
        #pragma unroll
        for (int j = 0; j < 4; ++j) {
            const int col = ocol0 + j * 16;
            const float bv = bias ? bias[col] : 0.f;
            #pragma unroll
            for (int r = 0; r < 4; ++r) {
                const int row = orow0 + i * 16 + r;
                const float v = acc[i][j][r] + bv;
                if (BF16_OUT)
                    ((ushort_t*)C)[(size_t)row * N + col] = f2bf(v);
                else
                    ((float*)C)[(size_t)row * N + col] = v;
            }
        }
    }
}

// ---------------------------------------------------------------------------
extern "C" void kernel_launch(void* const* d_in, const int* in_sizes, int n_in,
                              void* d_out, int out_size, void* d_ws, size_t ws_size,
                              hipStream_t stream) {
    const float* x     = (const float*)d_in[0];   // (2,2048,1024)
    const float* w_in  = (const float*)d_in[1];   // (3072,1024)
    const float* b_in  = (const float*)d_in[2];   // (3072,)
    const float* w_out = (const float*)d_in[3];   // (1024,1024)
    const float* b_out = (const float*)d_in[4];   // (1024,)
    float* out = (float*)d_out;                   // (2,2048,1024) fp32

    char* ws = (char*)d_ws;
    ushort_t* xb     = (ushort_t*)(ws);                      // 8 MB: x in bf16
    ushort_t* wob    = (ushort_t*)(ws + (8u  << 20));        // 2 MB: w_out bf16
    ushort_t* Pt     = (ushort_t*)(ws + (10u << 20));        // 2 MB: w_in_v^T bf16
    ushort_t* Wfb    = (ushort_t*)(ws + (12u << 20));        // 2 MB: fused weight bf16
    float*    bfused = (float*)   (ws + (14u << 20));        // 4 KB

    // prep
    cvt4<<<2048, 256, 0, stream>>>(x, xb, (2 * 2048 * 1024) / 4);
    cvt4<<<512,  256, 0, stream>>>(w_out, wob, (1024 * 1024) / 4);
    gather_tr<<<dim3(16, 16), 256, 0, stream>>>(w_in, Pt);
    fuse_bias<<<256, 256, 0, stream>>>(w_out, b_in, b_out, bfused);

    // Wf = w_out @ w_in_v^T  (M=N=K=1024), bf16 out
    gemm_abt<true><<<dim3(8, 8), 256, 0, stream>>>(wob, Pt, nullptr, (void*)Wfb, 1024, 1024);

    // out = x @ Wf^T + bfused  (M=4096, N=1024, K=1024), fp32 out
    gemm_abt<false><<<dim3(8, 32), 256, 0, stream>>>(xb, Wfb, bfused, (void*)out, 1024, 1024);
}

// Round 2
// 60.863 us; speedup vs baseline: 1.2507x; 1.2507x over previous
//
#include <hip/hip_runtime.h>

typedef unsigned short ushort_t;
typedef __bf16 bf16x8 __attribute__((ext_vector_type(8)));
typedef float f32x4 __attribute__((ext_vector_type(4)));

static __device__ __forceinline__ ushort_t f2bf(float f) {
    __bf16 b = (__bf16)f;   // RNE convert
    return __builtin_bit_cast(ushort_t, b);
}

#define GLOAD_LDS16(gptr, lptr)                                                        \
    __builtin_amdgcn_global_load_lds(                                                  \
        (const __attribute__((address_space(1))) void*)(gptr),                         \
        (__attribute__((address_space(3))) void*)(lptr), 16, 0, 0)

// ---------------------------------------------------------------------------
// Merged prep kernel. Block ranges:
//   [0,512)    : x fp32 -> bf16        (1,048,576 float4)
//   [512,576)  : w_out fp32 -> bf16    (262,144 float4)
//   [576,832)  : gather+transpose of w_in v-rows -> Pt bf16
//   [832,848)  : bfused[i] = b_out[i] + sum_j w_out[i][j]*b_in[r(j)]
__global__ __launch_bounds__(256)
void prep(const float* __restrict__ x, const float* __restrict__ w_in,
          const float* __restrict__ b_in, const float* __restrict__ w_out,
          const float* __restrict__ b_out,
          ushort_t* __restrict__ xb, ushort_t* __restrict__ wob,
          ushort_t* __restrict__ Pt, float* __restrict__ bfused) {
    __shared__ ushort_t tile[64][65];
    const int bx = blockIdx.x;
    const int t = threadIdx.x;

    if (bx < 512) {
        int i = bx * 256 + t;
        #pragma unroll
        for (int p = 0; p < 8; ++p, i += 131072) {
            float4 v = ((const float4*)x)[i];
            ushort4 o;
            o.x = f2bf(v.x); o.y = f2bf(v.y); o.z = f2bf(v.z); o.w = f2bf(v.w);
            ((ushort4*)xb)[i] = o;
        }
    } else if (bx < 576) {
        int i = (bx - 512) * 256 + t;
        #pragma unroll
        for (int p = 0; p < 16; ++p, i += 16384) {
            float4 v = ((const float4*)w_out)[i];
            ushort4 o;
            o.x = f2bf(v.x); o.y = f2bf(v.y); o.z = f2bf(v.z); o.w = f2bf(v.w);
            ((ushort4*)wob)[i] = o;
        }
    } else if (bx < 832) {
        const int g = bx - 576;
        const int gx = g & 15;        // v-channel tile (64 wide)
        const int gy = g >> 4;        // input-channel tile (64 wide)
        const int c0 = gy * 64;
        #pragma unroll
        for (int p = 0; p < 16; ++p) {
            int e = p * 256 + t;
            int j = e >> 6, c = e & 63;
            int r = gx * 192 + 128 + j;          // r(gx*64 + j)
            tile[j][c] = f2bf(w_in[(size_t)r * 1024 + c0 + c]);
        }
        __syncthreads();
        #pragma unroll
        for (int p = 0; p < 16; ++p) {
            int e = p * 256 + t;
            int c = e >> 6, j = e & 63;
            Pt[(size_t)(c0 + c) * 1024 + gx * 64 + j] = tile[j][c];
        }
    } else {
        const int w = t >> 6, lane = t & 63;
        const int rb = (bx - 832) * 64;
        for (int rr = 0; rr < 16; ++rr) {
            const int i = rb + rr * 4 + w;
            float s = 0.f;
            #pragma unroll
            for (int jj = 0; jj < 16; ++jj) {
                int j = jj * 64 + lane;
                int r = (j >> 6) * 192 + 128 + (j & 63);
                s += w_out[(size_t)i * 1024 + j] * b_in[r];
            }
            #pragma unroll
            for (int off = 32; off; off >>= 1) s += __shfl_down(s, off, 64);
            if (lane == 0) bfused[i] = s + b_out[i];
        }
    }
}

// ---------------------------------------------------------------------------
// C[M][N] = A[M][K] @ B[N][K]^T (+ bias[n]), bf16 in, fp32 or bf16 out.
// BK=32, global_load_lds width-16 staging, mfma_f32_16x16x32_bf16,
// m97 2-barrier structure. Wave grid WGM x WGN, per-wave out WM x WN.
template <int BM, int BN, int THREADS, int WGM, int WGN, bool BF16_OUT>
__global__ __launch_bounds__(THREADS)
void gemm_abt(const ushort_t* __restrict__ A, const ushort_t* __restrict__ B,
              const float* __restrict__ bias, void* __restrict__ C,
              const int K, const int N) {
    constexpr int WM = BM / WGM, WN = BN / WGN;
    constexpr int MI = WM / 16, NJ = WN / 16;
    constexpr int LA = (BM * 4) / THREADS;   // 8-elem chunks per thread for A tile
    constexpr int LB = (BN * 4) / THREADS;
    __shared__ alignas(16) ushort_t lsA[BM * 32];
    __shared__ alignas(16) ushort_t lsB[BN * 32];

    const int tid  = threadIdx.x;
    const int lane = tid & 63;
    const int wv   = tid >> 6;
    const int wr   = wv / WGN;
    const int wc   = wv % WGN;
    const int fr   = lane & 15;
    const int fq   = lane >> 4;

    const int rA = blockIdx.y * BM;
    const int rB = blockIdx.x * BN;

    f32x4 acc[MI][NJ] = {};

    for (int k0 = 0; k0 < K; k0 += 32) {
        #pragma unroll
        for (int q = 0; q < LA; ++q) {
            const int e8 = q * THREADS + tid;   // chunk index; row = e8>>2, col8 = e8&3
            GLOAD_LDS16(A + (size_t)(rA + (e8 >> 2)) * K + k0 + (e8 & 3) * 8,
                        &lsA[(size_t)(q * THREADS + wv * 64) * 8]);
        }
        #pragma unroll
        for (int q = 0; q < LB; ++q) {
            const int e8 = q * THREADS + tid;
            GLOAD_LDS16(B + (size_t)(rB + (e8 >> 2)) * K + k0 + (e8 & 3) * 8,
                        &lsB[(size_t)(q * THREADS + wv * 64) * 8]);
        }
        __syncthreads();   // drains vmcnt(0) -> staged tiles visible

        bf16x8 af[MI], bfv[NJ];
        #pragma unroll
        for (int i = 0; i < MI; ++i)
            af[i] = *(const bf16x8*)&lsA[(wr * WM + i * 16 + fr) * 32 + fq * 8];
        #pragma unroll
        for (int j = 0; j < NJ; ++j)
            bfv[j] = *(const bf16x8*)&lsB[(wc * WN + j * 16 + fr) * 32 + fq * 8];

        #pragma unroll
        for (int i = 0; i < MI; ++i)
            #pragma unroll
            for (int j = 0; j < NJ; ++j)
                acc[i][j] = __builtin_amdgcn_mfma_f32_16x16x32_bf16(af[i], bfv[j], acc[i][j], 0, 0, 0);

        __syncthreads();
    }

    // epilogue: within a 16x16 frag, row = fq*4 + r, col = fr
    const int orow0 = rA + wr * WM + fq * 4;
    const int ocol0 = rB + wc * WN + fr;
    #pragma unroll
    for (int i = 0; i < MI; ++i) {
        #pragma unroll
        for (int j = 0; j < NJ; ++j) {
            const int col = ocol0 + j * 16;
            const float bv = bias ? bias[col] : 0.f;
            #pragma unroll
            for (int r = 0; r < 4; ++r) {
                const int row = orow0 + i * 16 + r;
                const float v = acc[i][j][r] + bv;
                if (BF16_OUT)
                    ((ushort_t*)C)[(size_t)row * N + col] = f2bf(v);
                else
                    ((float*)C)[(size_t)row * N + col] = v;
            }
        }
    }
}

// ---------------------------------------------------------------------------
extern "C" void kernel_launch(void* const* d_in, const int* in_sizes, int n_in,
                              void* d_out, int out_size, void* d_ws, size_t ws_size,
                              hipStream_t stream) {
    const float* x     = (const float*)d_in[0];   // (2,2048,1024)
    const float* w_in  = (const float*)d_in[1];   // (3072,1024)
    const float* b_in  = (const float*)d_in[2];   // (3072,)
    const float* w_out = (const float*)d_in[3];   // (1024,1024)
    const float* b_out = (const float*)d_in[4];   // (1024,)
    float* out = (float*)d_out;                   // (2,2048,1024) fp32

    char* ws = (char*)d_ws;
    ushort_t* xb     = (ushort_t*)(ws);                      // 8 MB: x bf16
    ushort_t* wob    = (ushort_t*)(ws + (8u  << 20));        // 2 MB: w_out bf16
    ushort_t* Pt     = (ushort_t*)(ws + (10u << 20));        // 2 MB: w_in_v^T bf16
    ushort_t* Wfb    = (ushort_t*)(ws + (12u << 20));        // 2 MB: fused weight bf16
    float*    bfused = (float*)   (ws + (14u << 20));        // 4 KB

    // all prep in one launch
    prep<<<848, 256, 0, stream>>>(x, w_in, b_in, w_out, b_out, xb, wob, Pt, bfused);

    // Wf = w_out @ w_in_v^T  (M=N=K=1024), 64x64 tiles -> 256 blocks
    gemm_abt<64, 64, 256, 2, 2, true>
        <<<dim3(16, 16), 256, 0, stream>>>(wob, Pt, nullptr, (void*)Wfb, 1024, 1024);

    // out = x @ Wf^T + bfused  (M=4096, N=1024, K=1024), 128x128, 8 waves
    gemm_abt<128, 128, 512, 2, 4, false>
        <<<dim3(8, 32), 512, 0, stream>>>(xb, Wfb, bfused, (void*)out, 1024, 1024);
}